// Round 15
// baseline (47.404 us; speedup 1.0000x reference)
//
#include <hip/hip_runtime.h>
#include <hip/hip_bf16.h>
#include <cstddef>

typedef __attribute__((ext_vector_type(8))) short bf16x8;
typedef __attribute__((ext_vector_type(4))) float f32x4;

#define NB 4
#define CIN 64
#define COUT 64
#define HH 128
#define WW 128
#define TAPS 9
#define HW (HH * WW)

__device__ __forceinline__ unsigned short f2bf(float f) {
    union { float f; unsigned u; } v; v.f = f;
    unsigned u = v.u + 0x7FFFu + ((v.u >> 16) & 1u);   // RNE
    return (unsigned short)(u >> 16);
}

// B-frags in the per-(lane,slot) k-permutation the A-side builds locally:
// math slot L = s*8 + e; L<36: c = chunk*16 + 4g + L/9, tap = L%9; else 0-pad.
// wBv[((wv*20 + chunk*5 + s)*64 + lane)*8 + e],  o = wv*16 + (lane&15), g = lane>>4
__global__ void prep_weight(const float* __restrict__ w, unsigned short* __restrict__ wBv) {
    int idx = blockIdx.x * blockDim.x + threadIdx.x;
    if (idx >= 40960) return;
    int e    = idx & 7;
    int lane = (idx >> 3) & 63;
    int fid  = idx >> 9;               // wv*20 + chunk*5 + s
    int wv   = fid / 20;
    int rem  = fid - wv * 20;
    int chunk = rem / 5;
    int s     = rem - chunk * 5;
    int l15 = lane & 15, g = lane >> 4;
    int o  = wv * 16 + l15;
    int L  = s * 8 + e;                // local k within this g-group: 0..39
    unsigned short v = 0;
    if (L < 36) {
        int c   = chunk * 16 + 4 * g + L / 9;
        int tap = L % 9;
        v = f2bf(w[(o * CIN + c) * TAPS + tap]);
    }
    wBv[idx] = v;
}

__launch_bounds__(256)
__global__ void pac_conv(const float* __restrict__ x, const float* __restrict__ Kp,
                         const unsigned short* __restrict__ wBv,
                         const float* __restrict__ bias,
                         float* __restrict__ out) {
    // ZERO LDS, ZERO BARRIERS: lane (g,l15) stages channels 4g..4g+3 at pixel
    // l15 with the R6/R9/R10-PROVEN guarded-load pattern (no DPP anywhere).

    // XCD-chunked bijective swizzle (4096 % 8 == 0)
    const int blk0 = blockIdx.x;
    const int blk  = ((blk0 & 7) << 9) | (blk0 >> 3);

    const int wt = blk & 7;                   // 16-px tile
    const int h  = (blk >> 3) & (HH - 1);
    const int n  = blk >> 10;
    const int w0 = wt * 16;

    const int t    = threadIdx.x;
    const int lane = t & 63;
    const int wv   = __builtin_amdgcn_readfirstlane(t >> 6);
    const int l15  = lane & 15;               // pixel within tile AND output col
    const int g    = lane >> 4;               // k-group AND channel quad

    // per-pixel adapting kernel -> registers
    float kreg[TAPS];
    float ks = 0.f;
    const float* kp = Kp + ((size_t)n * TAPS * HH + h) * WW + w0 + l15;
    #pragma unroll
    for (int tap = 0; tap < TAPS; ++tap) {
        kreg[tap] = kp[(size_t)tap * HW];
        ks += kreg[tap];
    }
    const float inv = 1.0f / ks;

    // w-edge handling (R10-proven): base biased by -1 float; unsigned offsets
    const bool mL = (w0 == 0)       && (l15 == 0);
    const bool mR = (w0 == WW - 16) && (l15 == 15);
    const unsigned voffL = (mL ? 1u : (unsigned)l15) * 4u;                   // l=0
    const unsigned voffC = ((unsigned)l15 + 1u) * 4u;                        // l=1
    const unsigned voffR = (mR ? (unsigned)l15 : (unsigned)l15 + 2u) * 4u;   // l=2

    const float bval = bias[wv * 16 + l15];
    f32x4 acc = (f32x4){0.f, 0.f, 0.f, 0.f};

    #pragma unroll
    for (int chunk = 0; chunk < 4; ++chunk) {
        // ---- B-frags for this chunk (coalesced, issued early) ----
        const unsigned short* wfb =
            wBv + (((size_t)(wv * 20 + chunk * 5) << 6) + lane) * 8;   // +s*512
        bf16x8 bfr[5];
        #pragma unroll
        for (int s = 0; s < 5; ++s)
            bfr[s] = *reinterpret_cast<const bf16x8*>(wfb + (s << 9));

        // ---- stage 4 channels at pixel l15 (guarded scalar loads) ----
        float cch[4][TAPS];
        #pragma unroll
        for (int j = 0; j < 4; ++j) {
            const int c = chunk * 16 + 4 * g + j;
            const float* xb = x + (size_t)(n * CIN + c) * HW + w0 - 1;   // -1 bias
            float xv[TAPS];
            #pragma unroll
            for (int k = 0; k < 3; ++k) {
                const int hh2 = h + k - 1;
                const bool hok = (unsigned)hh2 < (unsigned)HH;
                const int hc = hok ? hh2 : (hh2 < 0 ? 0 : HH - 1);
                const float* p = xb + (size_t)hc * WW;
                float vL = *(const float*)((const char*)p + voffL);
                float vC = *(const float*)((const char*)p + voffC);
                float vR = *(const float*)((const char*)p + voffR);
                xv[k * 3 + 0] = (hok && !mL) ? vL : 0.f;
                xv[k * 3 + 1] = hok ? vC : 0.f;
                xv[k * 3 + 2] = (hok && !mR) ? vR : 0.f;
            }
            float s = 0.f;
            #pragma unroll
            for (int tap = 0; tap < TAPS; ++tap) s = fmaf(xv[tap], kreg[tap], s);
            const float d = s * inv;
            #pragma unroll
            for (int tap = 0; tap < TAPS; ++tap)
                cch[j][tap] = fmaf(kreg[tap], xv[tap] - d, d);
        }

        // ---- pack A-frags in the shared permutation: slot L = s*8 + e ----
        unsigned int fr[5][4];
        #pragma unroll
        for (int s = 0; s < 5; ++s) {
            #pragma unroll
            for (int i = 0; i < 4; ++i) {
                const int L0 = s * 8 + 2 * i, L1 = L0 + 1;
                const float f0 = (L0 < 36) ? cch[L0 / 9][L0 % 9] : 0.f;
                const float f1 = (L1 < 36) ? cch[L1 / 9][L1 % 9] : 0.f;
                union { __hip_bfloat162 h2; unsigned int u; } pk;
                pk.h2 = __float22bfloat162_rn(make_float2(f0, f1));
                fr[s][i] = pk.u;
            }
        }

        // ---- 5 MFMAs straight from registers (no LDS, no barrier) ----
        #pragma unroll
        for (int s = 0; s < 5; ++s) {
            union { unsigned int u[4]; bf16x8 f; } af;
            af.u[0] = fr[s][0]; af.u[1] = fr[s][1];
            af.u[2] = fr[s][2]; af.u[3] = fr[s][3];
            acc = __builtin_amdgcn_mfma_f32_16x16x32_bf16(af.f, bfr[s], acc, 0, 0, 0);
        }
    }

    // epilogue: D row = px = g*4+r, col = o = wv*16+l15 -> one float4 per thread
    float* op = out + (((size_t)n * COUT + wv * 16 + l15) * HH + h) * WW + w0 + g * 4;
    f32x4 v = acc;
    #pragma unroll
    for (int r = 0; r < 4; ++r) v[r] += bval;
    *reinterpret_cast<f32x4*>(op) = v;
}

extern "C" void kernel_launch(void* const* d_in, const int* in_sizes, int n_in,
                              void* d_out, int out_size, void* d_ws, size_t ws_size,
                              hipStream_t stream) {
    const float* x    = (const float*)d_in[0];
    const float* Kp   = (const float*)d_in[1];
    const float* wgt  = (const float*)d_in[2];
    const float* bias = (const float*)d_in[3];
    float* out = (float*)d_out;
    unsigned short* wBv = (unsigned short*)d_ws;             // 81920 B

    prep_weight<<<160, 256, 0, stream>>>(wgt, wBv);

    pac_conv<<<NB * HH * (WW / 16), 256, 0, stream>>>(x, Kp, wBv, bias, out);
}

// Round 16
// 29.235 us; speedup vs baseline: 1.6215x; 1.6215x over previous
//
#include <hip/hip_runtime.h>
#include <hip/hip_bf16.h>
#include <cstddef>

typedef __attribute__((ext_vector_type(8))) short bf16x8;
typedef __attribute__((ext_vector_type(4))) float f32x4;

#define NB 4
#define CIN 64
#define COUT 64
#define HH 128
#define WW 128
#define TAPS 9
#define HW (HH * WW)

__device__ __forceinline__ unsigned short f2bf(float f) {
    union { float f; unsigned u; } v; v.f = f;
    unsigned u = v.u + 0x7FFFu + ((v.u >> 16) & 1u);   // RNE
    return (unsigned short)(u >> 16);
}

// PROVEN R15 prep (absmax 0.015625): B-frags in the per-(lane,slot) permutation
// the A-side builds locally. Slot L = s*8 + e; L<36: c = chunk*16 + 4g + L/9,
// tap = L%9; else 0-pad. wBv[((ov*20 + chunk*5 + s)*64 + lane)*8 + e],
// o = ov*16 + (lane&15), g = lane>>4.
__global__ void prep_weight(const float* __restrict__ w, unsigned short* __restrict__ wBv) {
    int idx = blockIdx.x * blockDim.x + threadIdx.x;
    if (idx >= 40960) return;
    int e    = idx & 7;
    int lane = (idx >> 3) & 63;
    int fid  = idx >> 9;               // ov*20 + chunk*5 + s
    int ov   = fid / 20;
    int rem  = fid - ov * 20;
    int chunk = rem / 5;
    int s     = rem - chunk * 5;
    int l15 = lane & 15, g = lane >> 4;
    int o  = ov * 16 + l15;
    int L  = s * 8 + e;                // local k within this g-group: 0..39
    unsigned short v = 0;
    if (L < 36) {
        int c   = chunk * 16 + 4 * g + L / 9;
        int tap = L % 9;
        v = f2bf(w[(o * CIN + c) * TAPS + tap]);
    }
    wBv[idx] = v;
}

__launch_bounds__(256)
__global__ void pac_conv(const float* __restrict__ x, const float* __restrict__ Kp,
                         const unsigned short* __restrict__ wBv,
                         const float* __restrict__ bias,
                         float* __restrict__ out) {
    // ZERO LDS, ZERO BARRIERS, ZERO REDUNDANCY: block = 4 independent waves on
    // 4 adjacent rows; each wave stages its row-tile ONCE and produces all 64
    // outputs for it (4 B-sets x 5 MFMAs per chunk into acc[4]).

    // XCD-chunked bijective swizzle (1024 % 8 == 0)
    const int blk0 = blockIdx.x;
    const int blk  = ((blk0 & 7) << 7) | (blk0 >> 3);

    const int wt = blk & 7;                   // 16-px tile
    const int h0 = ((blk >> 3) & 31) * 4;     // 4-row group
    const int n  = blk >> 8;
    const int w0 = wt * 16;

    const int t    = threadIdx.x;
    const int lane = t & 63;
    const int wv   = __builtin_amdgcn_readfirstlane(t >> 6);  // ROW selector
    const int h    = h0 + wv;
    const int l15  = lane & 15;               // pixel within tile AND output col
    const int g    = lane >> 4;               // k-group AND channel quad

    // per-pixel adapting kernel -> registers
    float kreg[TAPS];
    float ks = 0.f;
    const float* kp = Kp + ((size_t)n * TAPS * HH + h) * WW + w0 + l15;
    #pragma unroll
    for (int tap = 0; tap < TAPS; ++tap) {
        kreg[tap] = kp[(size_t)tap * HW];
        ks += kreg[tap];
    }
    const float inv = 1.0f / ks;

    // w-edge handling (proven): base biased by -1 float; unsigned offsets
    const bool mL = (w0 == 0)       && (l15 == 0);
    const bool mR = (w0 == WW - 16) && (l15 == 15);
    const unsigned voffL = (mL ? 1u : (unsigned)l15) * 4u;                   // l=0
    const unsigned voffC = ((unsigned)l15 + 1u) * 4u;                        // l=1
    const unsigned voffR = (mR ? (unsigned)l15 : (unsigned)l15 + 2u) * 4u;   // l=2

    f32x4 acc[4];
    #pragma unroll
    for (int i = 0; i < 4; ++i) acc[i] = (f32x4){0.f, 0.f, 0.f, 0.f};

    #pragma unroll
    for (int chunk = 0; chunk < 4; ++chunk) {
        // ---- stage 4 channels at pixel l15 (PROVEN guarded scalar loads) ----
        float cch[4][TAPS];
        #pragma unroll
        for (int j = 0; j < 4; ++j) {
            const int c = chunk * 16 + 4 * g + j;
            const float* xb = x + (size_t)(n * CIN + c) * HW + w0 - 1;   // -1 bias
            float xv[TAPS];
            #pragma unroll
            for (int k = 0; k < 3; ++k) {
                const int hh2 = h + k - 1;
                const bool hok = (unsigned)hh2 < (unsigned)HH;
                const int hc = hok ? hh2 : (hh2 < 0 ? 0 : HH - 1);
                const float* p = xb + (size_t)hc * WW;
                float vL = *(const float*)((const char*)p + voffL);
                float vC = *(const float*)((const char*)p + voffC);
                float vR = *(const float*)((const char*)p + voffR);
                xv[k * 3 + 0] = (hok && !mL) ? vL : 0.f;
                xv[k * 3 + 1] = hok ? vC : 0.f;
                xv[k * 3 + 2] = (hok && !mR) ? vR : 0.f;
            }
            float s = 0.f;
            #pragma unroll
            for (int tap = 0; tap < TAPS; ++tap) s = fmaf(xv[tap], kreg[tap], s);
            const float d = s * inv;
            #pragma unroll
            for (int tap = 0; tap < TAPS; ++tap)
                cch[j][tap] = fmaf(kreg[tap], xv[tap] - d, d);
        }

        // ---- pack A-frags in the shared permutation: slot L = s*8 + e ----
        unsigned int fr[5][4];
        #pragma unroll
        for (int s = 0; s < 5; ++s) {
            #pragma unroll
            for (int i = 0; i < 4; ++i) {
                const int L0 = s * 8 + 2 * i, L1 = L0 + 1;
                const float f0 = (L0 < 36) ? cch[L0 / 9][L0 % 9] : 0.f;
                const float f1 = (L1 < 36) ? cch[L1 / 9][L1 % 9] : 0.f;
                union { __hip_bfloat162 h2; unsigned int u; } pk;
                pk.h2 = __float22bfloat162_rn(make_float2(f0, f1));
                fr[s][i] = pk.u;
            }
        }

        // ---- 4 output quads x 5 MFMAs, all from registers ----
        #pragma unroll
        for (int ov = 0; ov < 4; ++ov) {
            const unsigned short* wfb =
                wBv + (((size_t)(ov * 20 + chunk * 5) << 6) + lane) * 8;   // +s*512
            #pragma unroll
            for (int s = 0; s < 5; ++s) {
                bf16x8 bfrag = *reinterpret_cast<const bf16x8*>(wfb + (s << 9));
                union { unsigned int u[4]; bf16x8 f; } af;
                af.u[0] = fr[s][0]; af.u[1] = fr[s][1];
                af.u[2] = fr[s][2]; af.u[3] = fr[s][3];
                acc[ov] = __builtin_amdgcn_mfma_f32_16x16x32_bf16(af.f, bfrag, acc[ov], 0, 0, 0);
            }
        }
    }

    // epilogue: per ov, D row = px = g*4+r, col = o = ov*16+l15
    #pragma unroll
    for (int ov = 0; ov < 4; ++ov) {
        const int o = ov * 16 + l15;
        float* op = out + (((size_t)n * COUT + o) * HH + h) * WW + w0 + g * 4;
        f32x4 v = acc[ov];
        const float bv = bias[o];
        #pragma unroll
        for (int r = 0; r < 4; ++r) v[r] += bv;
        *reinterpret_cast<f32x4*>(op) = v;
    }
}

extern "C" void kernel_launch(void* const* d_in, const int* in_sizes, int n_in,
                              void* d_out, int out_size, void* d_ws, size_t ws_size,
                              hipStream_t stream) {
    const float* x    = (const float*)d_in[0];
    const float* Kp   = (const float*)d_in[1];
    const float* wgt  = (const float*)d_in[2];
    const float* bias = (const float*)d_in[3];
    float* out = (float*)d_out;
    unsigned short* wBv = (unsigned short*)d_ws;             // 81920 B

    prep_weight<<<160, 256, 0, stream>>>(wgt, wBv);

    pac_conv<<<NB * (HH / 4) * (WW / 16), 256, 0, stream>>>(x, Kp, wBv, bias, out);
}

// Round 17
// 29.133 us; speedup vs baseline: 1.6272x; 1.0035x over previous
//
#include <hip/hip_runtime.h>
#include <hip/hip_bf16.h>
#include <cstddef>

typedef __attribute__((ext_vector_type(8))) short bf16x8;
typedef __attribute__((ext_vector_type(4))) float f32x4;

#define NB 4
#define CIN 64
#define COUT 64
#define HH 128
#define WW 128
#define TAPS 9
#define HW (HH * WW)

__device__ __forceinline__ unsigned short f2bf(float f) {
    union { float f; unsigned u; } v; v.f = f;
    unsigned u = v.u + 0x7FFFu + ((v.u >> 16) & 1u);   // RNE
    return (unsigned short)(u >> 16);
}

// Fused setup: (a) PROVEN prep mapping (R15/R16, absmax 0.015625) on blocks
// 0..159; (b) streaming cache-warm of x+Kp on all 2048 blocks, sliced per-XCD
// to mirror pac_conv's swizzle (XCD k <-> n=k>>1, row-half k&1; 2.4 MB < 4 MB L2).
__global__ void setup_k(const float* __restrict__ w, unsigned short* __restrict__ wBv,
                        const float* __restrict__ x, const float* __restrict__ Kp) {
    // ---- streaming prefetch (sequential dwordx4, huge MLP) ----
    {
        const int k   = blockIdx.x & 7;            // XCD key (matches pac_conv blk0&7)
        const int m   = blockIdx.x >> 3;           // 0..255 within XCD group
        const int tid = m * 256 + threadIdx.x;     // 0..65535
        const int n   = k >> 1;
        const int r0  = (k & 1) * 64;

        // x slice: [64 ch][64 rows][128 px] = 524288 floats -> 8 per thread (exact)
        {
            const int off = tid * 8;
            const int c   = off >> 13;             // /(64*128)
            const int rem = off & 8191;
            const float* p = x + ((size_t)(n * CIN + c) * HH + r0 + (rem >> 7)) * WW + (rem & 127);
            f32x4 a = *reinterpret_cast<const f32x4*>(p);
            f32x4 b = *reinterpret_cast<const f32x4*>(p + 4);
            float s = a[0] + a[1] + a[2] + a[3] + b[0] + b[1] + b[2] + b[3];
            asm volatile("" :: "v"(s));            // keep loads live (rule #17)
        }
        // Kp slice: [9 taps][64 rows][128 px] = 73728 floats -> threads 0..9215 (exact)
        if (tid < 9216) {
            const int off = tid * 8;
            const int tap = off >> 13;
            const int rem = off & 8191;
            const float* p = Kp + ((size_t)(n * TAPS + tap) * HH + r0 + (rem >> 7)) * WW + (rem & 127);
            f32x4 a = *reinterpret_cast<const f32x4*>(p);
            f32x4 b = *reinterpret_cast<const f32x4*>(p + 4);
            float s = a[0] + a[1] + a[2] + a[3] + b[0] + b[1] + b[2] + b[3];
            asm volatile("" :: "v"(s));
        }
    }

    // ---- prep (PROVEN R15/R16 mapping, verbatim) ----
    int idx = blockIdx.x * blockDim.x + threadIdx.x;
    if (idx >= 40960) return;
    int e    = idx & 7;
    int lane = (idx >> 3) & 63;
    int fid  = idx >> 9;               // ov*20 + chunk*5 + s
    int ov   = fid / 20;
    int rem  = fid - ov * 20;
    int chunk = rem / 5;
    int s     = rem - chunk * 5;
    int l15 = lane & 15, g = lane >> 4;
    int o  = ov * 16 + l15;
    int L  = s * 8 + e;                // local k within this g-group: 0..39
    unsigned short v = 0;
    if (L < 36) {
        int c   = chunk * 16 + 4 * g + L / 9;
        int tap = L % 9;
        v = f2bf(w[(o * CIN + c) * TAPS + tap]);
    }
    wBv[idx] = v;
}

__launch_bounds__(256)
__global__ void pac_conv(const float* __restrict__ x, const float* __restrict__ Kp,
                         const unsigned short* __restrict__ wBv,
                         const float* __restrict__ bias,
                         float* __restrict__ out) {
    // R16 VERBATIM (29.2 us, absmax 0.015625): zero LDS, zero barriers, zero
    // redundancy. Block = 4 independent waves on 4 adjacent rows.

    // XCD-chunked bijective swizzle (1024 % 8 == 0)
    const int blk0 = blockIdx.x;
    const int blk  = ((blk0 & 7) << 7) | (blk0 >> 3);

    const int wt = blk & 7;                   // 16-px tile
    const int h0 = ((blk >> 3) & 31) * 4;     // 4-row group
    const int n  = blk >> 8;
    const int w0 = wt * 16;

    const int t    = threadIdx.x;
    const int lane = t & 63;
    const int wv   = __builtin_amdgcn_readfirstlane(t >> 6);  // ROW selector
    const int h    = h0 + wv;
    const int l15  = lane & 15;               // pixel within tile AND output col
    const int g    = lane >> 4;               // k-group AND channel quad

    // per-pixel adapting kernel -> registers
    float kreg[TAPS];
    float ks = 0.f;
    const float* kp = Kp + ((size_t)n * TAPS * HH + h) * WW + w0 + l15;
    #pragma unroll
    for (int tap = 0; tap < TAPS; ++tap) {
        kreg[tap] = kp[(size_t)tap * HW];
        ks += kreg[tap];
    }
    const float inv = 1.0f / ks;

    // w-edge handling (proven): base biased by -1 float; unsigned offsets
    const bool mL = (w0 == 0)       && (l15 == 0);
    const bool mR = (w0 == WW - 16) && (l15 == 15);
    const unsigned voffL = (mL ? 1u : (unsigned)l15) * 4u;                   // l=0
    const unsigned voffC = ((unsigned)l15 + 1u) * 4u;                        // l=1
    const unsigned voffR = (mR ? (unsigned)l15 : (unsigned)l15 + 2u) * 4u;   // l=2

    f32x4 acc[4];
    #pragma unroll
    for (int i = 0; i < 4; ++i) acc[i] = (f32x4){0.f, 0.f, 0.f, 0.f};

    #pragma unroll
    for (int chunk = 0; chunk < 4; ++chunk) {
        // ---- stage 4 channels at pixel l15 (proven guarded scalar loads) ----
        float cch[4][TAPS];
        #pragma unroll
        for (int j = 0; j < 4; ++j) {
            const int c = chunk * 16 + 4 * g + j;
            const float* xb = x + (size_t)(n * CIN + c) * HW + w0 - 1;   // -1 bias
            float xv[TAPS];
            #pragma unroll
            for (int k = 0; k < 3; ++k) {
                const int hh2 = h + k - 1;
                const bool hok = (unsigned)hh2 < (unsigned)HH;
                const int hc = hok ? hh2 : (hh2 < 0 ? 0 : HH - 1);
                const float* p = xb + (size_t)hc * WW;
                float vL = *(const float*)((const char*)p + voffL);
                float vC = *(const float*)((const char*)p + voffC);
                float vR = *(const float*)((const char*)p + voffR);
                xv[k * 3 + 0] = (hok && !mL) ? vL : 0.f;
                xv[k * 3 + 1] = hok ? vC : 0.f;
                xv[k * 3 + 2] = (hok && !mR) ? vR : 0.f;
            }
            float s = 0.f;
            #pragma unroll
            for (int tap = 0; tap < TAPS; ++tap) s = fmaf(xv[tap], kreg[tap], s);
            const float d = s * inv;
            #pragma unroll
            for (int tap = 0; tap < TAPS; ++tap)
                cch[j][tap] = fmaf(kreg[tap], xv[tap] - d, d);
        }

        // ---- pack A-frags in the shared permutation: slot L = s*8 + e ----
        unsigned int fr[5][4];
        #pragma unroll
        for (int s = 0; s < 5; ++s) {
            #pragma unroll
            for (int i = 0; i < 4; ++i) {
                const int L0 = s * 8 + 2 * i, L1 = L0 + 1;
                const float f0 = (L0 < 36) ? cch[L0 / 9][L0 % 9] : 0.f;
                const float f1 = (L1 < 36) ? cch[L1 / 9][L1 % 9] : 0.f;
                union { __hip_bfloat162 h2; unsigned int u; } pk;
                pk.h2 = __float22bfloat162_rn(make_float2(f0, f1));
                fr[s][i] = pk.u;
            }
        }

        // ---- 4 output quads x 5 MFMAs, all from registers ----
        #pragma unroll
        for (int ov = 0; ov < 4; ++ov) {
            const unsigned short* wfb =
                wBv + (((size_t)(ov * 20 + chunk * 5) << 6) + lane) * 8;   // +s*512
            #pragma unroll
            for (int s = 0; s < 5; ++s) {
                bf16x8 bfrag = *reinterpret_cast<const bf16x8*>(wfb + (s << 9));
                union { unsigned int u[4]; bf16x8 f; } af;
                af.u[0] = fr[s][0]; af.u[1] = fr[s][1];
                af.u[2] = fr[s][2]; af.u[3] = fr[s][3];
                acc[ov] = __builtin_amdgcn_mfma_f32_16x16x32_bf16(af.f, bfrag, acc[ov], 0, 0, 0);
            }
        }
    }

    // epilogue: per ov, D row = px = g*4+r, col = o = ov*16+l15
    #pragma unroll
    for (int ov = 0; ov < 4; ++ov) {
        const int o = ov * 16 + l15;
        float* op = out + (((size_t)n * COUT + o) * HH + h) * WW + w0 + g * 4;
        f32x4 v = acc[ov];
        const float bv = bias[o];
        #pragma unroll
        for (int r = 0; r < 4; ++r) v[r] += bv;
        *reinterpret_cast<f32x4*>(op) = v;
    }
}

extern "C" void kernel_launch(void* const* d_in, const int* in_sizes, int n_in,
                              void* d_out, int out_size, void* d_ws, size_t ws_size,
                              hipStream_t stream) {
    const float* x    = (const float*)d_in[0];
    const float* Kp   = (const float*)d_in[1];
    const float* wgt  = (const float*)d_in[2];
    const float* bias = (const float*)d_in[3];
    float* out = (float*)d_out;
    unsigned short* wBv = (unsigned short*)d_ws;             // 81920 B

    setup_k<<<2048, 256, 0, stream>>>(wgt, wBv, x, Kp);

    pac_conv<<<NB * (HH / 4) * (WW / 16), 256, 0, stream>>>(x, Kp, wBv, bias, out);
}